// Round 3
// baseline (2209.779 us; speedup 1.0000x reference)
//
#include <hip/hip_runtime.h>
#include <hip/hip_bf16.h>

// FraudGNN: 2-layer GraphSAGE (mean aggr) + linear head.
// N=100000 nodes, E=1600000 edges, feat 48 -> 32 -> 16 -> 2.
// fp32 inputs/weights/output (per reference); int edge_index (int64-autodetect).
//
// Key algebra: aggregation commutes with the linear layer:
//   mean(x[src]) @ Wl == segment_sum((x@Wl)[src]) / cnt
// so project to the OUTPUT dim first, then scatter (32- and 16-wide atomics
// instead of 48- and 32-wide).
//
// Own intermediates stored bf16 to keep workspace at 26 MB; fp32 math.

constexpr int NN = 100000;
constexpr int NE = 1600000;

__device__ __forceinline__ float bl(unsigned u) { return __uint_as_float(u << 16); }
__device__ __forceinline__ float bh(unsigned u) { return __uint_as_float(u & 0xffff0000u); }

// float -> bf16 bits, round-to-nearest-even (inputs finite)
__device__ __forceinline__ unsigned f2b(float x) {
    unsigned u = __float_as_uint(x);
    return (u + 0x7fffu + ((u >> 16) & 1u)) >> 16;
}
__device__ __forceinline__ unsigned pack2(float a, float b) {
    return f2b(a) | (f2b(b) << 16);
}

// ---- edge_index dtype autodetect -------------------------------------------
// If edge_index arrives as raw int64 (ids < 2^17), every high 32-bit word is 0.
// If narrowed to int32, odd words are random node ids (all-zero prob ~ 0).
// flag = 1 -> int64 layout (index word stride 2), 0 -> int32.
__global__ void detect_kernel(const int* __restrict__ ei, int* __restrict__ flag)
{
    __shared__ int s_any;
    if (threadIdx.x == 0) s_any = 0;
    __syncthreads();
    int v = 0;
    for (int i = threadIdx.x; i < 2048; i += blockDim.x) v |= ei[2 * i + 1];
    if (v != 0) s_any = 1;
    __syncthreads();
    if (threadIdx.x == 0) *flag = (s_any == 0) ? 1 : 0;
}

__device__ __forceinline__ int edge_src(const int* ei, int e, int sh) {
    return ei[(size_t)e << sh];
}
__device__ __forceinline__ int edge_dst(const int* ei, int e, int sh) {
    return ei[(size_t)(NE + e) << sh];
}

// ---- per-node dual linear: P = X@Wl, R = X@Wr (fp32 in, bf16 out) ----------
template <int DIN, int DOUT>
__global__ __launch_bounds__(256) void lin2_kernel(
    const float* __restrict__ X,
    const float* __restrict__ Wl,
    const float* __restrict__ Wr,
    __hip_bfloat16* __restrict__ P, __hip_bfloat16* __restrict__ R)
{
    __shared__ float sWl[DIN * DOUT];
    __shared__ float sWr[DIN * DOUT];
    for (int i = threadIdx.x; i < DIN * DOUT; i += blockDim.x) {
        sWl[i] = Wl[i];
        sWr[i] = Wr[i];
    }
    __syncthreads();
    int n = blockIdx.x * blockDim.x + threadIdx.x;
    if (n >= NN) return;

    float xr[DIN];
    const float4* xp = reinterpret_cast<const float4*>(X + (size_t)n * DIN);
#pragma unroll
    for (int i = 0; i < DIN / 4; ++i) {
        float4 u = xp[i];
        xr[i * 4 + 0] = u.x; xr[i * 4 + 1] = u.y;
        xr[i * 4 + 2] = u.z; xr[i * 4 + 3] = u.w;
    }

    float accp[DOUT], accr[DOUT];
#pragma unroll
    for (int j = 0; j < DOUT; ++j) { accp[j] = 0.f; accr[j] = 0.f; }
#pragma unroll
    for (int k = 0; k < DIN; ++k) {
        float xk = xr[k];
#pragma unroll
        for (int j = 0; j < DOUT; ++j) {
            accp[j] += xk * sWl[k * DOUT + j];
            accr[j] += xk * sWr[k * DOUT + j];
        }
    }

    uint4* pp = reinterpret_cast<uint4*>(P + (size_t)n * DOUT);
    uint4* rp = reinterpret_cast<uint4*>(R + (size_t)n * DOUT);
#pragma unroll
    for (int i = 0; i < DOUT / 8; ++i) {
        uint4 u, v;
        u.x = pack2(accp[i*8+0], accp[i*8+1]); u.y = pack2(accp[i*8+2], accp[i*8+3]);
        u.z = pack2(accp[i*8+4], accp[i*8+5]); u.w = pack2(accp[i*8+6], accp[i*8+7]);
        v.x = pack2(accr[i*8+0], accr[i*8+1]); v.y = pack2(accr[i*8+2], accr[i*8+3]);
        v.z = pack2(accr[i*8+4], accr[i*8+5]); v.w = pack2(accr[i*8+6], accr[i*8+7]);
        pp[i] = u;
        rp[i] = v;
    }
}

// ---- degree ----------------------------------------------------------------
__global__ __launch_bounds__(256) void deg_kernel(const int* __restrict__ ei,
                                                  const int* __restrict__ flag,
                                                  float* __restrict__ cnt)
{
    int e = blockIdx.x * blockDim.x + threadIdx.x;
    if (e >= NE) return;
    int d = edge_dst(ei, e, *flag);
    if ((unsigned)d < (unsigned)NN) atomicAdd(&cnt[d], 1.0f);
}

// ---- scatter-add bf16 rows of P (W bf16 per row) into fp32 msg -------------
template <int W>
__global__ __launch_bounds__(256) void scatter_kernel(
    const __hip_bfloat16* __restrict__ P,
    const int* __restrict__ ei, const int* __restrict__ flag,
    float* __restrict__ msg)
{
    constexpr int C = W / 8;  // uint4 chunks (8 bf16) per row
    int i = blockIdx.x * blockDim.x + threadIdx.x;
    if (i >= NE * C) return;
    int e = i / C;
    int c = i - e * C;
    int sh = *flag;
    int s = edge_src(ei, e, sh);
    int d = edge_dst(ei, e, sh);
    if ((unsigned)s >= (unsigned)NN || (unsigned)d >= (unsigned)NN) return;
    uint4 u = reinterpret_cast<const uint4*>(P + (size_t)s * W)[c];
    float* m = msg + (size_t)d * W + c * 8;
    atomicAdd(m + 0, bl(u.x)); atomicAdd(m + 1, bh(u.x));
    atomicAdd(m + 2, bl(u.y)); atomicAdd(m + 3, bh(u.y));
    atomicAdd(m + 4, bl(u.z)); atomicAdd(m + 5, bh(u.z));
    atomicAdd(m + 6, bl(u.w)); atomicAdd(m + 7, bh(u.w));
}

// ---- layer1 node update fused with layer2 projections ----------------------
__global__ __launch_bounds__(256) void node1_kernel(
    const float* __restrict__ msg1,            // [NN,32] fp32
    const float* __restrict__ cnt,
    const __hip_bfloat16* __restrict__ R1,     // [NN,32] bf16
    const float* __restrict__ b1,              // [32] fp32
    const float* __restrict__ W2l,             // [32,16] fp32
    const float* __restrict__ W2r,             // [32,16] fp32
    __hip_bfloat16* __restrict__ P2, __hip_bfloat16* __restrict__ R2)  // [NN,16]
{
    __shared__ float sWl[32 * 16], sWr[32 * 16], sb[32];
    for (int i = threadIdx.x; i < 32 * 16; i += blockDim.x) {
        sWl[i] = W2l[i];
        sWr[i] = W2r[i];
    }
    if (threadIdx.x < 32) sb[threadIdx.x] = b1[threadIdx.x];
    __syncthreads();
    int n = blockIdx.x * blockDim.x + threadIdx.x;
    if (n >= NN) return;

    float inv = 1.0f / fmaxf(cnt[n], 1.0f);
    float h[32];
    const float4* mp = reinterpret_cast<const float4*>(msg1 + (size_t)n * 32);
    const uint4*  rp = reinterpret_cast<const uint4*>(R1 + (size_t)n * 32);
#pragma unroll
    for (int i = 0; i < 4; ++i) {
        uint4 r = rp[i];
        float rr[8] = { bl(r.x), bh(r.x), bl(r.y), bh(r.y),
                        bl(r.z), bh(r.z), bl(r.w), bh(r.w) };
        float4 m0 = mp[i * 2], m1 = mp[i * 2 + 1];
        float mm[8] = { m0.x, m0.y, m0.z, m0.w, m1.x, m1.y, m1.z, m1.w };
#pragma unroll
        for (int j = 0; j < 8; ++j)
            h[i * 8 + j] = fmaxf(mm[j] * inv + rr[j] + sb[i * 8 + j], 0.f);
    }

    float accp[16], accr[16];
#pragma unroll
    for (int j = 0; j < 16; ++j) { accp[j] = 0.f; accr[j] = 0.f; }
#pragma unroll
    for (int k = 0; k < 32; ++k) {
        float hk = h[k];
#pragma unroll
        for (int j = 0; j < 16; ++j) {
            accp[j] += hk * sWl[k * 16 + j];
            accr[j] += hk * sWr[k * 16 + j];
        }
    }

    uint4* pp  = reinterpret_cast<uint4*>(P2 + (size_t)n * 16);
    uint4* rr2 = reinterpret_cast<uint4*>(R2 + (size_t)n * 16);
#pragma unroll
    for (int i = 0; i < 2; ++i) {
        uint4 u, v;
        u.x = pack2(accp[i*8+0], accp[i*8+1]); u.y = pack2(accp[i*8+2], accp[i*8+3]);
        u.z = pack2(accp[i*8+4], accp[i*8+5]); u.w = pack2(accp[i*8+6], accp[i*8+7]);
        v.x = pack2(accr[i*8+0], accr[i*8+1]); v.y = pack2(accr[i*8+2], accr[i*8+3]);
        v.z = pack2(accr[i*8+4], accr[i*8+5]); v.w = pack2(accr[i*8+6], accr[i*8+7]);
        pp[i] = u;
        rr2[i] = v;
    }
}

// ---- layer2 node update fused with final linear head -----------------------
__global__ __launch_bounds__(256) void node2_kernel(
    const float* __restrict__ msg2,            // [NN,16] fp32
    const float* __restrict__ cnt,
    const __hip_bfloat16* __restrict__ R2,     // [NN,16] bf16
    const float* __restrict__ b2,              // [16]
    const float* __restrict__ Wlin,            // [16,2]
    const float* __restrict__ blin,            // [2]
    float* __restrict__ out)                   // [NN,2] fp32
{
    __shared__ float sW[16 * 2], sb[16], sbl[2];
    if (threadIdx.x < 32) sW[threadIdx.x] = Wlin[threadIdx.x];
    else if (threadIdx.x < 48) sb[threadIdx.x - 32] = b2[threadIdx.x - 32];
    else if (threadIdx.x < 50) sbl[threadIdx.x - 48] = blin[threadIdx.x - 48];
    __syncthreads();
    int n = blockIdx.x * blockDim.x + threadIdx.x;
    if (n >= NN) return;

    float inv = 1.0f / fmaxf(cnt[n], 1.0f);
    const float4* mp = reinterpret_cast<const float4*>(msg2 + (size_t)n * 16);
    const uint4*  rp = reinterpret_cast<const uint4*>(R2 + (size_t)n * 16);
    float o0 = sbl[0], o1 = sbl[1];
#pragma unroll
    for (int i = 0; i < 2; ++i) {
        uint4 r = rp[i];
        float rr[8] = { bl(r.x), bh(r.x), bl(r.y), bh(r.y),
                        bl(r.z), bh(r.z), bl(r.w), bh(r.w) };
        float4 m0 = mp[i * 2], m1 = mp[i * 2 + 1];
        float mm[8] = { m0.x, m0.y, m0.z, m0.w, m1.x, m1.y, m1.z, m1.w };
#pragma unroll
        for (int j = 0; j < 8; ++j) {
            int k = i * 8 + j;
            float hv = fmaxf(mm[j] * inv + rr[j] + sb[k], 0.f);
            o0 += hv * sW[k * 2];
            o1 += hv * sW[k * 2 + 1];
        }
    }
    reinterpret_cast<float2*>(out)[n] = make_float2(o0, o1);
}

extern "C" void kernel_launch(void* const* d_in, const int* in_sizes, int n_in,
                              void* d_out, int out_size, void* d_ws, size_t ws_size,
                              hipStream_t stream)
{
    const float* x    = (const float*)d_in[0];
    const int*   ei   = (const int*)d_in[1];
    const float* W1l  = (const float*)d_in[2];
    const float* W1r  = (const float*)d_in[3];
    const float* b1   = (const float*)d_in[4];
    const float* W2l  = (const float*)d_in[5];
    const float* W2r  = (const float*)d_in[6];
    const float* b2   = (const float*)d_in[7];
    const float* Wlin = (const float*)d_in[8];
    const float* blin = (const float*)d_in[9];
    float* out = (float*)d_out;

    // ---- workspace layout (byte offsets, N = 100000) ----
    // [0      , 4N  )  cnt   fp32 [N]
    // [4N     , 132N)  msg1  fp32 [N,32]   (msg2 fp32 [N,16] aliases 4N..68N)
    // [132N   , 196N)  p1 bf16 [N,32]      (p2 bf16 [N,16] @132N, r2 @164N)
    // [196N   , 260N)  r1 bf16 [N,32]
    // [260N   , 260N+4) int64-detect flag
    // total: 26,000,004 bytes
    char* wsb = (char*)d_ws;
    float*          cnt  = (float*)(wsb);
    float*          msg1 = (float*)(wsb + (size_t)4   * NN);
    float*          msg2 = (float*)(wsb + (size_t)4   * NN);
    __hip_bfloat16* p1   = (__hip_bfloat16*)(wsb + (size_t)132 * NN);
    __hip_bfloat16* p2   = (__hip_bfloat16*)(wsb + (size_t)132 * NN);
    __hip_bfloat16* r2   = (__hip_bfloat16*)(wsb + (size_t)164 * NN);
    __hip_bfloat16* r1   = (__hip_bfloat16*)(wsb + (size_t)196 * NN);
    int*            flag = (int*)(wsb + (size_t)260 * NN);

    dim3 blk(256);
    dim3 gN((NN + 255) / 256);

    // zero cnt + msg1 (132N bytes)
    hipMemsetAsync(wsb, 0, (size_t)132 * NN, stream);
    detect_kernel<<<1, blk, 0, stream>>>(ei, flag);

    lin2_kernel<48, 32><<<gN, blk, 0, stream>>>(x, W1l, W1r, p1, r1);
    deg_kernel<<<(NE + 255) / 256, blk, 0, stream>>>(ei, flag, cnt);
    scatter_kernel<32><<<(NE * 4 + 255) / 256, blk, 0, stream>>>(p1, ei, flag, msg1);
    node1_kernel<<<gN, blk, 0, stream>>>(msg1, cnt, r1, b1, W2l, W2r, p2, r2);

    // re-zero msg2 region (aliases msg1's first 64N bytes)
    hipMemsetAsync(wsb + (size_t)4 * NN, 0, (size_t)64 * NN, stream);
    scatter_kernel<16><<<(NE * 2 + 255) / 256, blk, 0, stream>>>(p2, ei, flag, msg2);
    node2_kernel<<<gN, blk, 0, stream>>>(msg2, cnt, r2, b2, Wlin, blin, out);
}

// Round 4
// 379.133 us; speedup vs baseline: 5.8285x; 5.8285x over previous
//
#include <hip/hip_runtime.h>
#include <hip/hip_bf16.h>

// FraudGNN: 2-layer GraphSAGE (mean aggr) + linear head.
// N=100000, E=1600000, feat 48 -> 32 -> 16 -> 2. fp32 in/out, int edge_index.
//
// R3: replace float-atomic scatter (51.2M+25.6M device atomics, 38 G/s ceiling,
// 1.6 GB HBM write traffic per scatter) with on-device CSR build (3.2M int
// atomics) + per-node gather (zero float atomics, exclusive ownership).
//
// Algebra: mean(x[src]) @ Wl == segment_sum((x@Wl)[src]) / cnt  -> project
// to OUTPUT dim first, then aggregate 32/16-wide rows.

constexpr int NN  = 100000;
constexpr int NE  = 1600000;
constexpr int NCH = (NN + 255) / 256;   // 391 scan chunks

__device__ __forceinline__ float bl(unsigned u) { return __uint_as_float(u << 16); }
__device__ __forceinline__ float bh(unsigned u) { return __uint_as_float(u & 0xffff0000u); }
__device__ __forceinline__ unsigned f2b(float x) {
    unsigned u = __float_as_uint(x);
    return (u + 0x7fffu + ((u >> 16) & 1u)) >> 16;
}
__device__ __forceinline__ unsigned pack2(float a, float b) {
    return f2b(a) | (f2b(b) << 16);
}

// ---- edge_index dtype autodetect (int64 raw vs int32 narrowed) -------------
__global__ void detect_kernel(const int* __restrict__ ei, int* __restrict__ flag)
{
    __shared__ int s_any;
    if (threadIdx.x == 0) s_any = 0;
    __syncthreads();
    int v = 0;
    for (int i = threadIdx.x; i < 2048; i += blockDim.x) v |= ei[2 * i + 1];
    if (v != 0) s_any = 1;
    __syncthreads();
    if (threadIdx.x == 0) *flag = (s_any == 0) ? 1 : 0;
}
__device__ __forceinline__ int edge_src(const int* ei, int e, int sh) {
    return ei[(size_t)e << sh];
}
__device__ __forceinline__ int edge_dst(const int* ei, int e, int sh) {
    return ei[(size_t)(NE + e) << sh];
}

// ---- per-node dual linear: P = X@Wl, R = X@Wr (fp32 in, bf16 out) ----------
template <int DIN, int DOUT>
__global__ __launch_bounds__(256) void lin2_kernel(
    const float* __restrict__ X,
    const float* __restrict__ Wl,
    const float* __restrict__ Wr,
    __hip_bfloat16* __restrict__ P, __hip_bfloat16* __restrict__ R)
{
    __shared__ float sWl[DIN * DOUT];
    __shared__ float sWr[DIN * DOUT];
    for (int i = threadIdx.x; i < DIN * DOUT; i += blockDim.x) {
        sWl[i] = Wl[i];
        sWr[i] = Wr[i];
    }
    __syncthreads();
    int n = blockIdx.x * blockDim.x + threadIdx.x;
    if (n >= NN) return;

    float xr[DIN];
    const float4* xp = reinterpret_cast<const float4*>(X + (size_t)n * DIN);
#pragma unroll
    for (int i = 0; i < DIN / 4; ++i) {
        float4 u = xp[i];
        xr[i * 4 + 0] = u.x; xr[i * 4 + 1] = u.y;
        xr[i * 4 + 2] = u.z; xr[i * 4 + 3] = u.w;
    }
    float accp[DOUT], accr[DOUT];
#pragma unroll
    for (int j = 0; j < DOUT; ++j) { accp[j] = 0.f; accr[j] = 0.f; }
#pragma unroll
    for (int k = 0; k < DIN; ++k) {
        float xk = xr[k];
#pragma unroll
        for (int j = 0; j < DOUT; ++j) {
            accp[j] += xk * sWl[k * DOUT + j];
            accr[j] += xk * sWr[k * DOUT + j];
        }
    }
    uint4* pp = reinterpret_cast<uint4*>(P + (size_t)n * DOUT);
    uint4* rp = reinterpret_cast<uint4*>(R + (size_t)n * DOUT);
#pragma unroll
    for (int i = 0; i < DOUT / 8; ++i) {
        uint4 u, v;
        u.x = pack2(accp[i*8+0], accp[i*8+1]); u.y = pack2(accp[i*8+2], accp[i*8+3]);
        u.z = pack2(accp[i*8+4], accp[i*8+5]); u.w = pack2(accp[i*8+6], accp[i*8+7]);
        v.x = pack2(accr[i*8+0], accr[i*8+1]); v.y = pack2(accr[i*8+2], accr[i*8+3]);
        v.z = pack2(accr[i*8+4], accr[i*8+5]); v.w = pack2(accr[i*8+6], accr[i*8+7]);
        pp[i] = u;
        rp[i] = v;
    }
}

// ---- CSR build --------------------------------------------------------------
__global__ __launch_bounds__(256) void hist_kernel(const int* __restrict__ ei,
                                                   const int* __restrict__ flag,
                                                   int* __restrict__ deg)
{
    int e = blockIdx.x * blockDim.x + threadIdx.x;
    if (e >= NE) return;
    int d = edge_dst(ei, e, *flag);
    if ((unsigned)d < (unsigned)NN) atomicAdd(&deg[d], 1);
}

__device__ __forceinline__ int wave_incl_scan(int v, int lane) {
#pragma unroll
    for (int d = 1; d < 64; d <<= 1) {
        int t = __shfl_up(v, d, 64);
        if (lane >= d) v += t;
    }
    return v;
}

__global__ __launch_bounds__(256) void scanA_kernel(const int* __restrict__ deg,
                                                    int* __restrict__ chunkbuf)
{
    int i = blockIdx.x * 256 + threadIdx.x;
    int v = (i < NN) ? deg[i] : 0;
    int lane = threadIdx.x & 63, wid = threadIdx.x >> 6;
    int incl = wave_incl_scan(v, lane);
    __shared__ int ws[4];
    if (lane == 63) ws[wid] = incl;
    __syncthreads();
    if (threadIdx.x == 0)
        chunkbuf[blockIdx.x] = ws[0] + ws[1] + ws[2] + ws[3];
}

__global__ __launch_bounds__(256) void scanB_kernel(int* __restrict__ chunkbuf)
{
    __shared__ int s[NCH];
    for (int i = threadIdx.x; i < NCH; i += blockDim.x) s[i] = chunkbuf[i];
    __syncthreads();
    if (threadIdx.x == 0) {
        int run = 0;
        for (int i = 0; i < NCH; ++i) { int t = s[i]; s[i] = run; run += t; }
    }
    __syncthreads();
    for (int i = threadIdx.x; i < NCH; i += blockDim.x) chunkbuf[i] = s[i];
}

__global__ __launch_bounds__(256) void scanC_kernel(const int* __restrict__ deg,
                                                    const int* __restrict__ chunkbuf,
                                                    int* __restrict__ rowstart,
                                                    int* __restrict__ cursor)
{
    int i = blockIdx.x * 256 + threadIdx.x;
    int v = (i < NN) ? deg[i] : 0;
    int lane = threadIdx.x & 63, wid = threadIdx.x >> 6;
    int incl = wave_incl_scan(v, lane);
    __shared__ int ws[4];
    if (lane == 63) ws[wid] = incl;
    __syncthreads();
    int off = chunkbuf[blockIdx.x];
#pragma unroll
    for (int w = 0; w < 3; ++w)
        if (wid > w) off += ws[w];
    int excl = off + incl - v;
    if (i < NN) { rowstart[i] = excl; cursor[i] = excl; }
}

__global__ __launch_bounds__(256) void fill_kernel(const int* __restrict__ ei,
                                                   const int* __restrict__ flag,
                                                   int* __restrict__ cursor,
                                                   int* __restrict__ csr_src)
{
    int e = blockIdx.x * blockDim.x + threadIdx.x;
    if (e >= NE) return;
    int sh = *flag;
    int s = edge_src(ei, e, sh);
    int d = edge_dst(ei, e, sh);
    if ((unsigned)s >= (unsigned)NN || (unsigned)d >= (unsigned)NN) return;
    int pos = atomicAdd(&cursor[d], 1);
    csr_src[pos] = s;
}

// ---- layer1 aggregation: 4 lanes/node, h = relu(mean+self+b1) over r1 ------
__global__ __launch_bounds__(256) void gather1_kernel(
    const int* __restrict__ rowstart, const int* __restrict__ deg,
    const int* __restrict__ csr_src,
    const __hip_bfloat16* __restrict__ p1,
    __hip_bfloat16* __restrict__ r1,        // in: self-proj; out: h (in place)
    const float* __restrict__ b1)
{
    __shared__ float sb[32];
    if (threadIdx.x < 32) sb[threadIdx.x] = b1[threadIdx.x];
    __syncthreads();
    int t = blockIdx.x * 256 + threadIdx.x;
    int n = t >> 2, c = t & 3;
    if (n >= NN) return;
    int start = rowstart[n], dn = deg[n];

    float acc[8];
#pragma unroll
    for (int j = 0; j < 8; ++j) acc[j] = 0.f;
    const uint4* prow = reinterpret_cast<const uint4*>(p1);
    for (int k = 0; k < dn; ++k) {
        int s = csr_src[start + k];
        uint4 u = prow[(size_t)s * 4 + c];
        acc[0] += bl(u.x); acc[1] += bh(u.x);
        acc[2] += bl(u.y); acc[3] += bh(u.y);
        acc[4] += bl(u.z); acc[5] += bh(u.z);
        acc[6] += bl(u.w); acc[7] += bh(u.w);
    }
    float inv = 1.0f / fmaxf((float)dn, 1.0f);
    uint4* hrow = reinterpret_cast<uint4*>(r1);
    uint4 r = hrow[(size_t)n * 4 + c];
    float rr[8] = { bl(r.x), bh(r.x), bl(r.y), bh(r.y),
                    bl(r.z), bh(r.z), bl(r.w), bh(r.w) };
    float hv[8];
#pragma unroll
    for (int j = 0; j < 8; ++j)
        hv[j] = fmaxf(acc[j] * inv + rr[j] + sb[c * 8 + j], 0.f);
    uint4 o;
    o.x = pack2(hv[0], hv[1]); o.y = pack2(hv[2], hv[3]);
    o.z = pack2(hv[4], hv[5]); o.w = pack2(hv[6], hv[7]);
    hrow[(size_t)n * 4 + c] = o;
}

// ---- layer2 projections from h: P2 = h@W2l, R2 = h@W2r ---------------------
__global__ __launch_bounds__(256) void node1b_kernel(
    const __hip_bfloat16* __restrict__ H,      // [NN,32] bf16
    const float* __restrict__ W2l,             // [32,16]
    const float* __restrict__ W2r,             // [32,16]
    __hip_bfloat16* __restrict__ P2, __hip_bfloat16* __restrict__ R2)
{
    __shared__ float sWl[32 * 16], sWr[32 * 16];
    for (int i = threadIdx.x; i < 32 * 16; i += blockDim.x) {
        sWl[i] = W2l[i];
        sWr[i] = W2r[i];
    }
    __syncthreads();
    int n = blockIdx.x * blockDim.x + threadIdx.x;
    if (n >= NN) return;

    float h[32];
    const uint4* hp = reinterpret_cast<const uint4*>(H + (size_t)n * 32);
#pragma unroll
    for (int i = 0; i < 4; ++i) {
        uint4 u = hp[i];
        h[i*8+0] = bl(u.x); h[i*8+1] = bh(u.x);
        h[i*8+2] = bl(u.y); h[i*8+3] = bh(u.y);
        h[i*8+4] = bl(u.z); h[i*8+5] = bh(u.z);
        h[i*8+6] = bl(u.w); h[i*8+7] = bh(u.w);
    }
    float accp[16], accr[16];
#pragma unroll
    for (int j = 0; j < 16; ++j) { accp[j] = 0.f; accr[j] = 0.f; }
#pragma unroll
    for (int k = 0; k < 32; ++k) {
        float hk = h[k];
#pragma unroll
        for (int j = 0; j < 16; ++j) {
            accp[j] += hk * sWl[k * 16 + j];
            accr[j] += hk * sWr[k * 16 + j];
        }
    }
    uint4* pp = reinterpret_cast<uint4*>(P2 + (size_t)n * 16);
    uint4* rr = reinterpret_cast<uint4*>(R2 + (size_t)n * 16);
#pragma unroll
    for (int i = 0; i < 2; ++i) {
        uint4 u, v;
        u.x = pack2(accp[i*8+0], accp[i*8+1]); u.y = pack2(accp[i*8+2], accp[i*8+3]);
        u.z = pack2(accp[i*8+4], accp[i*8+5]); u.w = pack2(accp[i*8+6], accp[i*8+7]);
        v.x = pack2(accr[i*8+0], accr[i*8+1]); v.y = pack2(accr[i*8+2], accr[i*8+3]);
        v.z = pack2(accr[i*8+4], accr[i*8+5]); v.w = pack2(accr[i*8+6], accr[i*8+7]);
        pp[i] = u;
        rr[i] = v;
    }
}

// ---- layer2 aggregation fused with linear head: 2 lanes/node ---------------
__global__ __launch_bounds__(256) void gather2_kernel(
    const int* __restrict__ rowstart, const int* __restrict__ deg,
    const int* __restrict__ csr_src,
    const __hip_bfloat16* __restrict__ P2,
    const __hip_bfloat16* __restrict__ R2,
    const float* __restrict__ b2,       // [16]
    const float* __restrict__ Wlin,     // [16,2]
    const float* __restrict__ blin,     // [2]
    float* __restrict__ out)            // [NN,2]
{
    __shared__ float sb[16], sW[32], sbl[2];
    if (threadIdx.x < 16) sb[threadIdx.x] = b2[threadIdx.x];
    else if (threadIdx.x < 48) sW[threadIdx.x - 16] = Wlin[threadIdx.x - 16];
    else if (threadIdx.x < 50) sbl[threadIdx.x - 48] = blin[threadIdx.x - 48];
    __syncthreads();
    int t = blockIdx.x * 256 + threadIdx.x;
    int n = t >> 1, c = t & 1;
    if (n >= NN) return;
    int start = rowstart[n], dn = deg[n];

    float acc[8];
#pragma unroll
    for (int j = 0; j < 8; ++j) acc[j] = 0.f;
    const uint4* prow = reinterpret_cast<const uint4*>(P2);
    for (int k = 0; k < dn; ++k) {
        int s = csr_src[start + k];
        uint4 u = prow[(size_t)s * 2 + c];
        acc[0] += bl(u.x); acc[1] += bh(u.x);
        acc[2] += bl(u.y); acc[3] += bh(u.y);
        acc[4] += bl(u.z); acc[5] += bh(u.z);
        acc[6] += bl(u.w); acc[7] += bh(u.w);
    }
    float inv = 1.0f / fmaxf((float)dn, 1.0f);
    uint4 r = reinterpret_cast<const uint4*>(R2)[(size_t)n * 2 + c];
    float rr[8] = { bl(r.x), bh(r.x), bl(r.y), bh(r.y),
                    bl(r.z), bh(r.z), bl(r.w), bh(r.w) };
    float o0 = 0.f, o1 = 0.f;
#pragma unroll
    for (int j = 0; j < 8; ++j) {
        int k = c * 8 + j;
        float hv = fmaxf(acc[j] * inv + rr[j] + sb[k], 0.f);
        o0 += hv * sW[k * 2];
        o1 += hv * sW[k * 2 + 1];
    }
    o0 += __shfl_xor(o0, 1, 64);
    o1 += __shfl_xor(o1, 1, 64);
    if (c == 0)
        reinterpret_cast<float2*>(out)[n] = make_float2(o0 + sbl[0], o1 + sbl[1]);
}

extern "C" void kernel_launch(void* const* d_in, const int* in_sizes, int n_in,
                              void* d_out, int out_size, void* d_ws, size_t ws_size,
                              hipStream_t stream)
{
    const float* x    = (const float*)d_in[0];
    const int*   ei   = (const int*)d_in[1];
    const float* W1l  = (const float*)d_in[2];
    const float* W1r  = (const float*)d_in[3];
    const float* b1   = (const float*)d_in[4];
    const float* W2l  = (const float*)d_in[5];
    const float* W2r  = (const float*)d_in[6];
    const float* b2   = (const float*)d_in[7];
    const float* Wlin = (const float*)d_in[8];
    const float* blin = (const float*)d_in[9];
    float* out = (float*)d_out;

    // ---- workspace layout (bytes) ----
    // [0        , 400000  ) deg       int[N]
    // [400000   , 800000  ) rowstart  int[N]
    // [800000   , 1200000 ) cursor    int[N]
    // [1200000  , 1201564 ) chunkbuf  int[NCH]
    // [1204000  , 1204004 ) flag
    // [1600000  , 8000000 ) csr_src   int[E]
    // [8000000  , 14400000) p1 bf16[N,32]  (later: p2 bf16[N,16] @8000000,
    //                                              r2 bf16[N,16] @11200000)
    // [14400000 , 20800000) r1 bf16[N,32]  (h written in place)
    // total 20.8 MB
    char* wsb = (char*)d_ws;
    int* deg      = (int*)(wsb);
    int* rowstart = (int*)(wsb + 400000);
    int* cursor   = (int*)(wsb + 800000);
    int* chunkbuf = (int*)(wsb + 1200000);
    int* flag     = (int*)(wsb + 1204000);
    int* csr_src  = (int*)(wsb + 1600000);
    __hip_bfloat16* p1 = (__hip_bfloat16*)(wsb + 8000000);
    __hip_bfloat16* p2 = (__hip_bfloat16*)(wsb + 8000000);
    __hip_bfloat16* r2 = (__hip_bfloat16*)(wsb + 11200000);
    __hip_bfloat16* r1 = (__hip_bfloat16*)(wsb + 14400000);

    dim3 blk(256);
    int gE = (NE + 255) / 256;

    hipMemsetAsync(deg, 0, 400000, stream);              // zero degree histogram
    detect_kernel<<<1, blk, 0, stream>>>(ei, flag);

    lin2_kernel<48, 32><<<NCH, blk, 0, stream>>>(x, W1l, W1r, p1, r1);

    hist_kernel<<<gE, blk, 0, stream>>>(ei, flag, deg);
    scanA_kernel<<<NCH, blk, 0, stream>>>(deg, chunkbuf);
    scanB_kernel<<<1, blk, 0, stream>>>(chunkbuf);
    scanC_kernel<<<NCH, blk, 0, stream>>>(deg, chunkbuf, rowstart, cursor);
    fill_kernel<<<gE, blk, 0, stream>>>(ei, flag, cursor, csr_src);

    gather1_kernel<<<(NN * 4 + 255) / 256, blk, 0, stream>>>(
        rowstart, deg, csr_src, p1, r1, b1);
    node1b_kernel<<<NCH, blk, 0, stream>>>(r1, W2l, W2r, p2, r2);
    gather2_kernel<<<(NN * 2 + 255) / 256, blk, 0, stream>>>(
        rowstart, deg, csr_src, p2, r2, b2, Wlin, blin, out);
}

// Round 5
// 239.083 us; speedup vs baseline: 9.2427x; 1.5858x over previous
//
#include <hip/hip_runtime.h>
#include <hip/hip_bf16.h>

// FraudGNN: 2-layer GraphSAGE (mean aggr) + linear head.
// N=100000, E=1600000, feat 48 -> 32 -> 16 -> 2. fp32 in/out, int edge_index.
//
// R5: replace {global-atomic hist, 3-kernel scan, atomic fill (105 MB of
// write-amplified HBM traffic)} with a 2-level counting sort:
//   bucket1: coarse bucket by dst>>8, per-block LDS hist + range reservation
//            -> packed (src<<8|dstlocal) writes in contiguous runs (~1.7x amp)
//   bucket2: one WG per bucket, LDS hist/scan/cursors -> csr_src writes land
//            in an 18 KB L2-hot region (dense lines, zero global atomics)
// Algebra: mean(x[src]) @ Wl == segment_sum((x@Wl)[src]) / cnt -> project to
// OUTPUT dim first, then aggregate 32/16-wide rows by gather.

constexpr int NN  = 100000;
constexpr int NE  = 1600000;
constexpr int NCH = (NN + 255) / 256;   // 391 node chunks
constexpr int NB  = 391;                // buckets = dst >> 8
constexpr int CAP = 4608;               // per-bucket capacity (mean 4096, ~8 sigma)
constexpr int T1  = 4096;               // edges per bucket1 block

__device__ __forceinline__ float bl(unsigned u) { return __uint_as_float(u << 16); }
__device__ __forceinline__ float bh(unsigned u) { return __uint_as_float(u & 0xffff0000u); }
__device__ __forceinline__ unsigned f2b(float x) {
    unsigned u = __float_as_uint(x);
    return (u + 0x7fffu + ((u >> 16) & 1u)) >> 16;
}
__device__ __forceinline__ unsigned pack2(float a, float b) {
    return f2b(a) | (f2b(b) << 16);
}

// ---- edge_index dtype autodetect (int64 raw vs int32 narrowed) -------------
__global__ void detect_kernel(const int* __restrict__ ei, int* __restrict__ flag)
{
    __shared__ int s_any;
    if (threadIdx.x == 0) s_any = 0;
    __syncthreads();
    int v = 0;
    for (int i = threadIdx.x; i < 2048; i += blockDim.x) v |= ei[2 * i + 1];
    if (v != 0) s_any = 1;
    __syncthreads();
    if (threadIdx.x == 0) *flag = (s_any == 0) ? 1 : 0;
}
__device__ __forceinline__ int edge_src(const int* ei, int e, int sh) {
    return ei[(size_t)e << sh];
}
__device__ __forceinline__ int edge_dst(const int* ei, int e, int sh) {
    return ei[(size_t)(NE + e) << sh];
}

__device__ __forceinline__ int wave_incl_scan(int v, int lane) {
#pragma unroll
    for (int d = 1; d < 64; d <<= 1) {
        int t = __shfl_up(v, d, 64);
        if (lane >= d) v += t;
    }
    return v;
}

// ---- per-node dual linear: P = X@Wl, R = X@Wr (fp32 in, bf16 out) ----------
template <int DIN, int DOUT>
__global__ __launch_bounds__(256) void lin2_kernel(
    const float* __restrict__ X,
    const float* __restrict__ Wl,
    const float* __restrict__ Wr,
    __hip_bfloat16* __restrict__ P, __hip_bfloat16* __restrict__ R)
{
    __shared__ float sWl[DIN * DOUT];
    __shared__ float sWr[DIN * DOUT];
    for (int i = threadIdx.x; i < DIN * DOUT; i += blockDim.x) {
        sWl[i] = Wl[i];
        sWr[i] = Wr[i];
    }
    __syncthreads();
    int n = blockIdx.x * blockDim.x + threadIdx.x;
    if (n >= NN) return;

    float xr[DIN];
    const float4* xp = reinterpret_cast<const float4*>(X + (size_t)n * DIN);
#pragma unroll
    for (int i = 0; i < DIN / 4; ++i) {
        float4 u = xp[i];
        xr[i * 4 + 0] = u.x; xr[i * 4 + 1] = u.y;
        xr[i * 4 + 2] = u.z; xr[i * 4 + 3] = u.w;
    }
    float accp[DOUT], accr[DOUT];
#pragma unroll
    for (int j = 0; j < DOUT; ++j) { accp[j] = 0.f; accr[j] = 0.f; }
#pragma unroll
    for (int k = 0; k < DIN; ++k) {
        float xk = xr[k];
#pragma unroll
        for (int j = 0; j < DOUT; ++j) {
            accp[j] += xk * sWl[k * DOUT + j];
            accr[j] += xk * sWr[k * DOUT + j];
        }
    }
    uint4* pp = reinterpret_cast<uint4*>(P + (size_t)n * DOUT);
    uint4* rp = reinterpret_cast<uint4*>(R + (size_t)n * DOUT);
#pragma unroll
    for (int i = 0; i < DOUT / 8; ++i) {
        uint4 u, v;
        u.x = pack2(accp[i*8+0], accp[i*8+1]); u.y = pack2(accp[i*8+2], accp[i*8+3]);
        u.z = pack2(accp[i*8+4], accp[i*8+5]); u.w = pack2(accp[i*8+6], accp[i*8+7]);
        v.x = pack2(accr[i*8+0], accr[i*8+1]); v.y = pack2(accr[i*8+2], accr[i*8+3]);
        v.z = pack2(accr[i*8+4], accr[i*8+5]); v.w = pack2(accr[i*8+6], accr[i*8+7]);
        pp[i] = u;
        rp[i] = v;
    }
}

// ---- pass 1: coarse bucket sort of edges by dst>>8 --------------------------
__global__ __launch_bounds__(256) void bucket1_kernel(
    const int* __restrict__ ei, const int* __restrict__ flag,
    int* __restrict__ bsize, unsigned* __restrict__ bbuf)
{
    __shared__ int hist[NB], base[NB], cur[NB];
    for (int i = threadIdx.x; i < NB; i += 256) { hist[i] = 0; cur[i] = 0; }
    __syncthreads();
    int sh = *flag;
    int e0 = blockIdx.x * T1;
    int e1 = min(e0 + T1, NE);
    // phase 1: count
    for (int e = e0 + threadIdx.x; e < e1; e += 256) {
        int d = edge_dst(ei, e, sh);
        if ((unsigned)d < (unsigned)NN) atomicAdd(&hist[d >> 8], 1);
    }
    __syncthreads();
    // phase 2: reserve global ranges (one atomic per nonzero bucket per block)
    for (int b = threadIdx.x; b < NB; b += 256) {
        int h = hist[b];
        base[b] = h ? atomicAdd(&bsize[b], h) : 0;
    }
    __syncthreads();
    // phase 3: write packed (src<<8 | dst_local); runs per bucket contiguous
    for (int e = e0 + threadIdx.x; e < e1; e += 256) {
        int s = edge_src(ei, e, sh);
        int d = edge_dst(ei, e, sh);
        if ((unsigned)s >= (unsigned)NN || (unsigned)d >= (unsigned)NN) continue;
        int b = d >> 8;
        int pos = base[b] + atomicAdd(&cur[b], 1);
        if (pos < CAP)
            bbuf[(size_t)b * CAP + pos] = ((unsigned)s << 8) | (unsigned)(d & 255);
    }
}

// ---- bucket-start scan (391 entries; trivial) -------------------------------
__global__ void bscan_kernel(const int* __restrict__ bsize, int* __restrict__ bstart)
{
    if (threadIdx.x == 0 && blockIdx.x == 0) {
        int run = 0;
        for (int b = 0; b < NB; ++b) {
            bstart[b] = run;
            run += min(bsize[b], CAP);
        }
    }
}

// ---- pass 2: per-bucket CSR fill, deg/rowstart emit (all LDS atomics) ------
__global__ __launch_bounds__(256) void bucket2_kernel(
    const int* __restrict__ bsize, const int* __restrict__ bstart,
    const unsigned* __restrict__ bbuf,
    int* __restrict__ deg, int* __restrict__ rowstart, int* __restrict__ csr_src)
{
    __shared__ int ldeg[256], lcur[256], ws[4];
    int b = blockIdx.x;
    int S  = min(bsize[b], CAP);
    int bs = bstart[b];
    const unsigned* bp = bbuf + (size_t)b * CAP;

    ldeg[threadIdx.x] = 0;
    __syncthreads();
    for (int i = threadIdx.x; i < S; i += 256)
        atomicAdd(&ldeg[bp[i] & 255u], 1);
    __syncthreads();

    int v = ldeg[threadIdx.x];
    int lane = threadIdx.x & 63, wid = threadIdx.x >> 6;
    int incl = wave_incl_scan(v, lane);
    if (lane == 63) ws[wid] = incl;
    __syncthreads();
    int off = 0;
#pragma unroll
    for (int w = 0; w < 3; ++w)
        if (wid > w) off += ws[w];
    int excl = off + incl - v;

    int node = (b << 8) + threadIdx.x;
    if (node < NN) {
        deg[node] = v;
        rowstart[node] = bs + excl;
    }
    lcur[threadIdx.x] = excl;
    __syncthreads();

    for (int i = threadIdx.x; i < S; i += 256) {
        unsigned pk = bp[i];
        int loc = pk & 255u;
        int pos = atomicAdd(&lcur[loc], 1);
        csr_src[bs + pos] = (int)(pk >> 8);
    }
}

// ---- layer1 aggregation: 4 lanes/node, h = relu(mean+self+b1) over r1 ------
__global__ __launch_bounds__(256) void gather1_kernel(
    const int* __restrict__ rowstart, const int* __restrict__ deg,
    const int* __restrict__ csr_src,
    const __hip_bfloat16* __restrict__ p1,
    __hip_bfloat16* __restrict__ r1,        // in: self-proj; out: h (in place)
    const float* __restrict__ b1)
{
    __shared__ float sb[32];
    if (threadIdx.x < 32) sb[threadIdx.x] = b1[threadIdx.x];
    __syncthreads();
    int t = blockIdx.x * 256 + threadIdx.x;
    int n = t >> 2, c = t & 3;
    if (n >= NN) return;
    int start = rowstart[n], dn = deg[n];

    float acc[8];
#pragma unroll
    for (int j = 0; j < 8; ++j) acc[j] = 0.f;
    const uint4* prow = reinterpret_cast<const uint4*>(p1);
    for (int k = 0; k < dn; ++k) {
        int s = csr_src[start + k];
        uint4 u = prow[(size_t)s * 4 + c];
        acc[0] += bl(u.x); acc[1] += bh(u.x);
        acc[2] += bl(u.y); acc[3] += bh(u.y);
        acc[4] += bl(u.z); acc[5] += bh(u.z);
        acc[6] += bl(u.w); acc[7] += bh(u.w);
    }
    float inv = 1.0f / fmaxf((float)dn, 1.0f);
    uint4* hrow = reinterpret_cast<uint4*>(r1);
    uint4 r = hrow[(size_t)n * 4 + c];
    float rr[8] = { bl(r.x), bh(r.x), bl(r.y), bh(r.y),
                    bl(r.z), bh(r.z), bl(r.w), bh(r.w) };
    float hv[8];
#pragma unroll
    for (int j = 0; j < 8; ++j)
        hv[j] = fmaxf(acc[j] * inv + rr[j] + sb[c * 8 + j], 0.f);
    uint4 o;
    o.x = pack2(hv[0], hv[1]); o.y = pack2(hv[2], hv[3]);
    o.z = pack2(hv[4], hv[5]); o.w = pack2(hv[6], hv[7]);
    hrow[(size_t)n * 4 + c] = o;
}

// ---- layer2 projections from h: P2 = h@W2l, R2 = h@W2r ---------------------
__global__ __launch_bounds__(256) void node1b_kernel(
    const __hip_bfloat16* __restrict__ H,      // [NN,32] bf16
    const float* __restrict__ W2l,             // [32,16]
    const float* __restrict__ W2r,             // [32,16]
    __hip_bfloat16* __restrict__ P2, __hip_bfloat16* __restrict__ R2)
{
    __shared__ float sWl[32 * 16], sWr[32 * 16];
    for (int i = threadIdx.x; i < 32 * 16; i += blockDim.x) {
        sWl[i] = W2l[i];
        sWr[i] = W2r[i];
    }
    __syncthreads();
    int n = blockIdx.x * blockDim.x + threadIdx.x;
    if (n >= NN) return;

    float h[32];
    const uint4* hp = reinterpret_cast<const uint4*>(H + (size_t)n * 32);
#pragma unroll
    for (int i = 0; i < 4; ++i) {
        uint4 u = hp[i];
        h[i*8+0] = bl(u.x); h[i*8+1] = bh(u.x);
        h[i*8+2] = bl(u.y); h[i*8+3] = bh(u.y);
        h[i*8+4] = bl(u.z); h[i*8+5] = bh(u.z);
        h[i*8+6] = bl(u.w); h[i*8+7] = bh(u.w);
    }
    float accp[16], accr[16];
#pragma unroll
    for (int j = 0; j < 16; ++j) { accp[j] = 0.f; accr[j] = 0.f; }
#pragma unroll
    for (int k = 0; k < 32; ++k) {
        float hk = h[k];
#pragma unroll
        for (int j = 0; j < 16; ++j) {
            accp[j] += hk * sWl[k * 16 + j];
            accr[j] += hk * sWr[k * 16 + j];
        }
    }
    uint4* pp = reinterpret_cast<uint4*>(P2 + (size_t)n * 16);
    uint4* rr = reinterpret_cast<uint4*>(R2 + (size_t)n * 16);
#pragma unroll
    for (int i = 0; i < 2; ++i) {
        uint4 u, v;
        u.x = pack2(accp[i*8+0], accp[i*8+1]); u.y = pack2(accp[i*8+2], accp[i*8+3]);
        u.z = pack2(accp[i*8+4], accp[i*8+5]); u.w = pack2(accp[i*8+6], accp[i*8+7]);
        v.x = pack2(accr[i*8+0], accr[i*8+1]); v.y = pack2(accr[i*8+2], accr[i*8+3]);
        v.z = pack2(accr[i*8+4], accr[i*8+5]); v.w = pack2(accr[i*8+6], accr[i*8+7]);
        pp[i] = u;
        rr[i] = v;
    }
}

// ---- layer2 aggregation fused with linear head: 2 lanes/node ---------------
__global__ __launch_bounds__(256) void gather2_kernel(
    const int* __restrict__ rowstart, const int* __restrict__ deg,
    const int* __restrict__ csr_src,
    const __hip_bfloat16* __restrict__ P2,
    const __hip_bfloat16* __restrict__ R2,
    const float* __restrict__ b2,       // [16]
    const float* __restrict__ Wlin,     // [16,2]
    const float* __restrict__ blin,     // [2]
    float* __restrict__ out)            // [NN,2]
{
    __shared__ float sb[16], sW[32], sbl[2];
    if (threadIdx.x < 16) sb[threadIdx.x] = b2[threadIdx.x];
    else if (threadIdx.x < 48) sW[threadIdx.x - 16] = Wlin[threadIdx.x - 16];
    else if (threadIdx.x < 50) sbl[threadIdx.x - 48] = blin[threadIdx.x - 48];
    __syncthreads();
    int t = blockIdx.x * 256 + threadIdx.x;
    int n = t >> 1, c = t & 1;
    if (n >= NN) return;
    int start = rowstart[n], dn = deg[n];

    float acc[8];
#pragma unroll
    for (int j = 0; j < 8; ++j) acc[j] = 0.f;
    const uint4* prow = reinterpret_cast<const uint4*>(P2);
    for (int k = 0; k < dn; ++k) {
        int s = csr_src[start + k];
        uint4 u = prow[(size_t)s * 2 + c];
        acc[0] += bl(u.x); acc[1] += bh(u.x);
        acc[2] += bl(u.y); acc[3] += bh(u.y);
        acc[4] += bl(u.z); acc[5] += bh(u.z);
        acc[6] += bl(u.w); acc[7] += bh(u.w);
    }
    float inv = 1.0f / fmaxf((float)dn, 1.0f);
    uint4 r = reinterpret_cast<const uint4*>(R2)[(size_t)n * 2 + c];
    float rr[8] = { bl(r.x), bh(r.x), bl(r.y), bh(r.y),
                    bl(r.z), bh(r.z), bl(r.w), bh(r.w) };
    float o0 = 0.f, o1 = 0.f;
#pragma unroll
    for (int j = 0; j < 8; ++j) {
        int k = c * 8 + j;
        float hv = fmaxf(acc[j] * inv + rr[j] + sb[k], 0.f);
        o0 += hv * sW[k * 2];
        o1 += hv * sW[k * 2 + 1];
    }
    o0 += __shfl_xor(o0, 1, 64);
    o1 += __shfl_xor(o1, 1, 64);
    if (c == 0)
        reinterpret_cast<float2*>(out)[n] = make_float2(o0 + sbl[0], o1 + sbl[1]);
}

extern "C" void kernel_launch(void* const* d_in, const int* in_sizes, int n_in,
                              void* d_out, int out_size, void* d_ws, size_t ws_size,
                              hipStream_t stream)
{
    const float* x    = (const float*)d_in[0];
    const int*   ei   = (const int*)d_in[1];
    const float* W1l  = (const float*)d_in[2];
    const float* W1r  = (const float*)d_in[3];
    const float* b1   = (const float*)d_in[4];
    const float* W2l  = (const float*)d_in[5];
    const float* W2r  = (const float*)d_in[6];
    const float* b2   = (const float*)d_in[7];
    const float* Wlin = (const float*)d_in[8];
    const float* blin = (const float*)d_in[9];
    float* out = (float*)d_out;

    // ---- workspace layout (bytes), total ~20.81 MB ----
    // [0       , 4       ) flag
    // [64      , 1628    ) bsize  int[NB]
    // [2048    , 3612    ) bstart int[NB]
    // [4096    , 404096  ) deg    int[N]
    // [404096  , 804096  ) rowstart int[N]
    // [804096  , 7204096 ) csr_src int[E]          (6.4 MB)
    // [7204096 , 14411008) bbuf u32[NB*CAP]        (7.21 MB)
    //      after bucket2: p1 bf16[N,32] aliases here (6.4 MB);
    //      later p2 bf16[N,16] @7204096, r2 bf16[N,16] @10404096
    // [14411008, 20811008) r1 bf16[N,32]           (h written in place)
    char* wsb = (char*)d_ws;
    int*      flag     = (int*)(wsb);
    int*      bsize    = (int*)(wsb + 64);
    int*      bstart   = (int*)(wsb + 2048);
    int*      deg      = (int*)(wsb + 4096);
    int*      rowstart = (int*)(wsb + 404096);
    int*      csr_src  = (int*)(wsb + 804096);
    unsigned* bbuf     = (unsigned*)(wsb + 7204096);
    __hip_bfloat16* p1 = (__hip_bfloat16*)(wsb + 7204096);
    __hip_bfloat16* p2 = (__hip_bfloat16*)(wsb + 7204096);
    __hip_bfloat16* r2 = (__hip_bfloat16*)(wsb + 10404096);
    __hip_bfloat16* r1 = (__hip_bfloat16*)(wsb + 14411008);

    dim3 blk(256);

    hipMemsetAsync(bsize, 0, NB * sizeof(int), stream);
    detect_kernel<<<1, blk, 0, stream>>>(ei, flag);

    bucket1_kernel<<<(NE + T1 - 1) / T1, blk, 0, stream>>>(ei, flag, bsize, bbuf);
    bscan_kernel<<<1, 64, 0, stream>>>(bsize, bstart);
    bucket2_kernel<<<NB, blk, 0, stream>>>(bsize, bstart, bbuf, deg, rowstart, csr_src);

    // lin2 AFTER bucket2: p1/r1 overwrite the bucket buffer region
    lin2_kernel<48, 32><<<NCH, blk, 0, stream>>>(x, W1l, W1r, p1, r1);

    gather1_kernel<<<(NN * 4 + 255) / 256, blk, 0, stream>>>(
        rowstart, deg, csr_src, p1, r1, b1);
    node1b_kernel<<<NCH, blk, 0, stream>>>(r1, W2l, W2r, p2, r2);
    gather2_kernel<<<(NN * 2 + 255) / 256, blk, 0, stream>>>(
        rowstart, deg, csr_src, p2, r2, b2, Wlin, blin, out);
}